// Round 7
// baseline (724.200 us; speedup 1.0000x reference)
//
#include <hip/hip_runtime.h>

// GATRotationRegressor — round 7: two independent single-wave pipelines per
// 128-thread workgroup (one batch element per wave, private LDS slices),
// VGPR trimmed below the 128 cliff (xin removed; x staged in LDS).
// B=16384, J=24, IN=3, H=128, HEADS=4, C=32, OUT=6, L=3.

#define J 24
#define HB 136   // bf16 LDS row stride in shorts (272 B, 16B-aligned)
#define YS 68    // fp32 overlay row stride in words (= HB shorts)

typedef __attribute__((ext_vector_type(8))) short short8;
typedef __attribute__((ext_vector_type(4))) float f32x4;

// bf16 weights prepared once per launch:
// [0)      Wt[l][n][k]   3*128*128 = 49152
// [49152)  w1t[m][k]     64*128    = 8192
// [57344)  wa[l][j][k]   3*16*128  = 6144  (j<4: a_s head j; 4..7: a_d; 8..15: 0)
// [63488)  w2t[o][m]     16*64     = 1024  (o<6 real, else 0)
__device__ unsigned short g_wt[64512];

__constant__ int c_deg[J] = {4,3,3,3,3,3,3,3,3,5,2,2,3,3,3,2,3,3,3,3,3,3,2,2};
__constant__ int c_inc[J][5] = {
  {1,2,3,0,0},{0,4,1,0,0},{0,5,2,0,0},{0,6,3,0,0},{1,7,4,0,0},{2,8,5,0,0},
  {3,9,6,0,0},{4,10,7,0,0},{5,11,8,0,0},{6,12,13,14,9},{7,10,0,0,0},{8,11,0,0,0},
  {9,15,12,0,0},{9,16,13,0,0},{9,17,14,0,0},{12,15,0,0,0},{13,18,16,0,0},{14,19,17,0,0},
  {16,20,18,0,0},{17,21,19,0,0},{18,22,20,0,0},{19,23,21,0,0},{20,22,0,0,0},{21,23,0,0,0}
};

__device__ __forceinline__ unsigned short f2bf(float f) {
  unsigned u = __builtin_bit_cast(unsigned, f);
  u = (u + 0x7FFFu + ((u >> 16) & 1u)) >> 16;   // RNE
  return (unsigned short)u;
}
__device__ __forceinline__ float bf2f(unsigned short u) {
  return __builtin_bit_cast(float, (unsigned)u << 16);
}

__global__ __launch_bounds__(256) void prep_weights(
    const float* __restrict__ gat_w, const float* __restrict__ att_s,
    const float* __restrict__ att_d, const float* __restrict__ w1,
    const float* __restrict__ w2)
{
  const int idx = blockIdx.x * 256 + threadIdx.x;
  if (idx < 49152) {
    const int l = idx >> 14, rem = idx & 16383, n = rem >> 7, k = rem & 127;
    g_wt[idx] = f2bf(gat_w[l*16384 + k*128 + n]);
  } else if (idx < 57344) {
    const int i2 = idx - 49152, m = i2 >> 7, k = i2 & 127;
    g_wt[idx] = f2bf(w1[k*64 + m]);
  } else if (idx < 63488) {
    const int i2 = idx - 57344;
    const int l = i2 >> 11, r = i2 & 2047, j = r >> 7, k = r & 127;
    float v = 0.f;
    if (j < 8) {
      const int sd = j >> 2, hhh = j & 3;
      const float* av = (sd ? att_d : att_s) + (l*4 + hhh)*32;
      const float* wp = gat_w + l*16384 + k*128 + hhh*32;
#pragma unroll 8
      for (int c = 0; c < 32; ++c) v += wp[c] * av[c];
    }
    g_wt[idx] = f2bf(v);
  } else if (idx < 64512) {
    const int i2 = idx - 63488, o = i2 >> 6, m = i2 & 63;
    g_wt[idx] = f2bf(o < 6 ? w2[m*6 + o] : 0.f);
  }
}

__global__ __launch_bounds__(128) void gat_fused(
    const float* __restrict__ x,     const float* __restrict__ in_w,  const float* __restrict__ in_b,
    const float* __restrict__ res_w, const float* __restrict__ res_b, const float* __restrict__ pos,
    const float* __restrict__ gat_b, const float* __restrict__ ln_g,  const float* __restrict__ ln_b,
    const float* __restrict__ b1,    const float* __restrict__ lng2,  const float* __restrict__ lnb2,
    const float* __restrict__ b2,    float* __restrict__ out)
{
  // Two waves per block; each wave owns one batch element + one LDS slice.
  __shared__ __align__(16) unsigned short s_hb_a [2*J*HB];  // h bf16; later yln bf16
  __shared__ __align__(16) unsigned short s_xlb_a[2*J*HB];  // xl bf16; later y1 fp32 overlay
  __shared__ float s_asd_a[2*J*8];
  __shared__ float s_alp_a[2*J*20];
  __shared__ float s_x_a[2*72];

  const int wv2 = threadIdx.x >> 6;       // wave id 0..1
  const int tid = threadIdx.x & 63;       // lane
  const long b  = (long)blockIdx.x*2 + wv2;

  unsigned short* s_hb  = s_hb_a  + wv2*(J*HB);
  unsigned short* s_xlb = s_xlb_a + wv2*(J*HB);
  float* s_asd = s_asd_a + wv2*(J*8);
  float* s_alp = s_alp_a + wv2*(J*20);
  float* s_x   = s_x_a   + wv2*72;

  const int l16 = tid & 15, q = tid >> 4;
  const int g = tid >> 3, c8 = tid & 7, cb = c8*16, hh = c8 >> 1;
  const int arow0 = l16;                          // M-tile 0 rows 0..15
  const int arow1 = (l16 < 8) ? 16 + l16 : 23;    // M-tile 1, clamped (rows 24..31 pad)

  // ---- P0: stage this wave's x (coalesced, wave-private) ----
  s_x[tid] = x[b*72 + tid];
  if (tid < 8) s_x[64 + tid] = x[b*72 + 64 + tid];

  // ---- P1: input projection -> vh (fp32 master) + s_hb (bf16) ----
  float vh[3][16];
#pragma unroll
  for (int i = 0; i < 3; ++i) {
    const int j = g + 8*i;
    const float x0 = s_x[j*3], x1 = s_x[j*3+1], x2 = s_x[j*3+2];
    short8 p0, p1;
#pragma unroll
    for (int c4 = 0; c4 < 4; ++c4) {
      const float4 w0 = *(const float4*)&in_w[      cb + c4*4];
      const float4 w1v= *(const float4*)&in_w[128 + cb + c4*4];
      const float4 w2v= *(const float4*)&in_w[256 + cb + c4*4];
      const float4 bb = *(const float4*)&in_b[      cb + c4*4];
      const float4 pp = *(const float4*)&pos[j*128 + cb + c4*4];
      float v[4];
      v[0] = x0*w0.x + x1*w1v.x + x2*w2v.x + bb.x + pp.x;
      v[1] = x0*w0.y + x1*w1v.y + x2*w2v.y + bb.y + pp.y;
      v[2] = x0*w0.z + x1*w1v.z + x2*w2v.z + bb.z + pp.z;
      v[3] = x0*w0.w + x1*w1v.w + x2*w2v.w + bb.w + pp.w;
#pragma unroll
      for (int cc = 0; cc < 4; ++cc) {
        const int c = c4*4 + cc;
        vh[i][c] = v[cc];
        if (c < 8) p0[c] = (short)f2bf(v[cc]); else p1[c-8] = (short)f2bf(v[cc]);
      }
    }
    *(short8*)&s_hb[j*HB + cb]     = p0;
    *(short8*)&s_hb[j*HB + cb + 8] = p1;
  }
  __syncthreads();

  // ---- GAT layers ----
  for (int l = 0; l < 3; ++l) {
    // === L1: xl = h@W (bf16 out) + fused logits = h@Wa ===
    {
      const unsigned short* Wl = &g_wt[l*16384];
#pragma unroll
      for (int nt = 0; nt < 8; ++nt) {
        f32x4 acc0 = {0,0,0,0}, acc1 = {0,0,0,0};
#pragma unroll
        for (int ks = 0; ks < 4; ++ks) {
          const short8 bfr = *(const short8*)&Wl[(nt*16 + l16)*128 + ks*32 + q*8];
          const short8 a0 = *(const short8*)&s_hb[arow0*HB + ks*32 + q*8];
          const short8 a1 = *(const short8*)&s_hb[arow1*HB + ks*32 + q*8];
          acc0 = __builtin_amdgcn_mfma_f32_16x16x32_bf16(a0, bfr, acc0, 0, 0, 0);
          acc1 = __builtin_amdgcn_mfma_f32_16x16x32_bf16(a1, bfr, acc1, 0, 0, 0);
        }
        const int col = nt*16 + l16;
#pragma unroll
        for (int r = 0; r < 4; ++r) s_xlb[(q*4 + r)*HB + col] = f2bf(acc0[r]);
        if (q < 2) {
#pragma unroll
          for (int r = 0; r < 4; ++r) s_xlb[(16 + q*4 + r)*HB + col] = f2bf(acc1[r]);
        }
      }
      // logits
      const unsigned short* Wa = &g_wt[57344 + l*2048];
      f32x4 la0 = {0,0,0,0}, la1 = {0,0,0,0};
#pragma unroll
      for (int ks = 0; ks < 4; ++ks) {
        const short8 ba = *(const short8*)&Wa[l16*128 + ks*32 + q*8];
        const short8 a0 = *(const short8*)&s_hb[arow0*HB + ks*32 + q*8];
        const short8 a1 = *(const short8*)&s_hb[arow1*HB + ks*32 + q*8];
        la0 = __builtin_amdgcn_mfma_f32_16x16x32_bf16(a0, ba, la0, 0, 0, 0);
        la1 = __builtin_amdgcn_mfma_f32_16x16x32_bf16(a1, ba, la1, 0, 0, 0);
      }
      if (l16 < 8) {
#pragma unroll
        for (int r = 0; r < 4; ++r) s_asd[(q*4 + r)*8 + l16] = la0[r];
        if (q < 2) {
#pragma unroll
          for (int r = 0; r < 4; ++r) s_asd[(16 + q*4 + r)*8 + l16] = la1[r];
        }
      }
    }
    __syncthreads();

    // === L2: scatter-softmax (96 items per wave, 2 passes) ===
#pragma unroll
    for (int it = 0; it < 2; ++it) {
      const int item = tid + it*64;
      if (item < 96) {
        const int r = item >> 2, hh2 = item & 3;
        const int dg = c_deg[r];
        const float ad = s_asd[r*8 + 4 + hh2];
        float ev[5];
        float m = -1e30f;
#pragma unroll
        for (int e = 0; e < 5; ++e) if (e < dg) {
          float ee = s_asd[c_inc[r][e]*8 + hh2] + ad;
          ee = (ee >= 0.f) ? ee : 0.2f*ee;
          ev[e] = ee;
          m = fmaxf(m, ee);
        }
        float den = 0.f;
#pragma unroll
        for (int e = 0; e < 5; ++e) if (e < dg) { ev[e] = __expf(ev[e]-m); den += ev[e]; }
        const float inv = 1.f/den;
#pragma unroll
        for (int e = 0; e < 5; ++e) if (e < dg) s_alp[(r*5+e)*4 + hh2] = ev[e]*inv;
      }
    }
    __syncthreads();

    // === L3: aggregate + elu + LN (shfl stats) + apply (+res at l==2) ===
#pragma unroll
    for (int i = 0; i < 3; ++i) {
      const int r = g + 8*i;
      const int dg = c_deg[r];
      float ov[16];
#pragma unroll
      for (int c4 = 0; c4 < 4; ++c4) {
        const float4 gb4 = *(const float4*)&gat_b[l*128 + cb + c4*4];
        ov[c4*4+0]=gb4.x; ov[c4*4+1]=gb4.y; ov[c4*4+2]=gb4.z; ov[c4*4+3]=gb4.w;
      }
#pragma unroll
      for (int e = 0; e < 5; ++e) if (e < dg) {
        const float al = s_alp[(r*5+e)*4 + hh];
        const unsigned short* xp = &s_xlb[c_inc[r][e]*HB + cb];
        const short8 xa = *(const short8*)xp;
        const short8 xb = *(const short8*)(xp + 8);
#pragma unroll
        for (int c = 0; c < 8; ++c) {
          ov[c]   += al * bf2f((unsigned short)xa[c]);
          ov[8+c] += al * bf2f((unsigned short)xb[c]);
        }
      }
      float s = 0.f, s2 = 0.f;
#pragma unroll
      for (int c = 0; c < 16; ++c) {
        float v = ov[c];
        v = (v > 0.f) ? v : (__expf(v) - 1.f);   // elu
        ov[c] = v;
        s += v; s2 += v*v;
      }
#pragma unroll
      for (int off = 1; off < 8; off <<= 1) {
        s  += __shfl_xor(s,  off, 64);
        s2 += __shfl_xor(s2, off, 64);
      }
      const float mean = s * (1.f/128.f);
      const float rstd = rsqrtf(s2 * (1.f/128.f) - mean*mean + 1e-5f);

      short8 p0, p1;
      if (l == 2) {
        const float x0 = s_x[r*3], x1 = s_x[r*3+1], x2 = s_x[r*3+2];
#pragma unroll
        for (int c4 = 0; c4 < 4; ++c4) {
          const float4 lg4 = *(const float4*)&ln_g[l*128 + cb + c4*4];
          const float4 lb4 = *(const float4*)&ln_b[l*128 + cb + c4*4];
          const float4 rw0 = *(const float4*)&res_w[      cb + c4*4];
          const float4 rw1 = *(const float4*)&res_w[128 + cb + c4*4];
          const float4 rw2 = *(const float4*)&res_w[256 + cb + c4*4];
          const float4 rb4 = *(const float4*)&res_b[      cb + c4*4];
          const float lgv[4] = {lg4.x, lg4.y, lg4.z, lg4.w};
          const float lbv[4] = {lb4.x, lb4.y, lb4.z, lb4.w};
          const float r0[4]  = {rw0.x, rw0.y, rw0.z, rw0.w};
          const float r1[4]  = {rw1.x, rw1.y, rw1.z, rw1.w};
          const float r2[4]  = {rw2.x, rw2.y, rw2.z, rw2.w};
          const float rb[4]  = {rb4.x, rb4.y, rb4.z, rb4.w};
#pragma unroll
          for (int cc = 0; cc < 4; ++cc) {
            const int c = c4*4 + cc;
            float v = (ov[c]-mean)*rstd*lgv[cc] + lbv[cc] + vh[i][c];
            v += x0*r0[cc] + x1*r1[cc] + x2*r2[cc] + rb[cc];
            vh[i][c] = v;
            if (c < 8) p0[c] = (short)f2bf(v); else p1[c-8] = (short)f2bf(v);
          }
        }
      } else {
#pragma unroll
        for (int c4 = 0; c4 < 4; ++c4) {
          const float4 lg4 = *(const float4*)&ln_g[l*128 + cb + c4*4];
          const float4 lb4 = *(const float4*)&ln_b[l*128 + cb + c4*4];
          const float lgv[4] = {lg4.x, lg4.y, lg4.z, lg4.w};
          const float lbv[4] = {lb4.x, lb4.y, lb4.z, lb4.w};
#pragma unroll
          for (int cc = 0; cc < 4; ++cc) {
            const int c = c4*4 + cc;
            float v = (ov[c]-mean)*rstd*lgv[cc] + lbv[cc];
            if (l > 0) v += vh[i][c];
            vh[i][c] = v;
            if (c < 8) p0[c] = (short)f2bf(v); else p1[c-8] = (short)f2bf(v);
          }
        }
      }
      *(short8*)&s_hb[r*HB + cb]     = p0;
      *(short8*)&s_hb[r*HB + cb + 8] = p1;
    }
    __syncthreads();
  }

  // ---- F1: y1 = relu(h @ w1t + b1), fp32 -> overlay on s_xlb (N=64, stride YS) ----
  {
    const unsigned short* W1 = &g_wt[49152];
    float* s_y = (float*)s_xlb;
#pragma unroll
    for (int nt = 0; nt < 4; ++nt) {
      const float bv = b1[nt*16 + l16];
      f32x4 acc0 = {bv,bv,bv,bv}, acc1 = {bv,bv,bv,bv};
#pragma unroll
      for (int ks = 0; ks < 4; ++ks) {
        const short8 bfr = *(const short8*)&W1[(nt*16 + l16)*128 + ks*32 + q*8];
        const short8 a0 = *(const short8*)&s_hb[arow0*HB + ks*32 + q*8];
        const short8 a1 = *(const short8*)&s_hb[arow1*HB + ks*32 + q*8];
        acc0 = __builtin_amdgcn_mfma_f32_16x16x32_bf16(a0, bfr, acc0, 0, 0, 0);
        acc1 = __builtin_amdgcn_mfma_f32_16x16x32_bf16(a1, bfr, acc1, 0, 0, 0);
      }
      const int col = nt*16 + l16;
#pragma unroll
      for (int r = 0; r < 4; ++r) s_y[(q*4 + r)*YS + col] = fmaxf(acc0[r], 0.f);
      if (q < 2) {
#pragma unroll
        for (int r = 0; r < 4; ++r) s_y[(16 + q*4 + r)*YS + col] = fmaxf(acc1[r], 0.f);
      }
    }
  }
  __syncthreads();

  // ---- F2: LN(64) + yln -> s_hb (bf16) ----
  if (tid < 48) {
    const int row = tid >> 1, half = tid & 1;
    const float* yr = (const float*)s_xlb + row*YS + half*32;
    float yv[32];
    float s = 0.f, s2 = 0.f;
#pragma unroll
    for (int c4 = 0; c4 < 8; ++c4) {
      const float4 v4 = *(const float4*)&yr[c4*4];
      yv[c4*4+0]=v4.x; yv[c4*4+1]=v4.y; yv[c4*4+2]=v4.z; yv[c4*4+3]=v4.w;
      s += v4.x+v4.y+v4.z+v4.w;
      s2 += v4.x*v4.x + v4.y*v4.y + v4.z*v4.z + v4.w*v4.w;
    }
    s  += __shfl_xor(s,  1, 64);
    s2 += __shfl_xor(s2, 1, 64);
    const float mean = s * (1.f/64.f);
    const float rstd = rsqrtf(s2 * (1.f/64.f) - mean*mean + 1e-5f);
    short8 pk[4];
#pragma unroll
    for (int c = 0; c < 32; ++c) {
      const int m = half*32 + c;
      const float yl = (yv[c]-mean)*rstd*lng2[m] + lnb2[m];
      pk[c >> 3][c & 7] = (short)f2bf(yl);
    }
#pragma unroll
    for (int p = 0; p < 4; ++p)
      *(short8*)&s_hb[row*HB + half*32 + p*8] = pk[p];
  }
  __syncthreads();

  // ---- F3: out = yln @ w2t + b2 (M=24, N=6(16), K=64) ----
  {
    const unsigned short* W2 = &g_wt[63488];
    const short8 bf0 = *(const short8*)&W2[l16*64 + q*8];
    const short8 bf1 = *(const short8*)&W2[l16*64 + 32 + q*8];
    const float bv = (l16 < 6) ? b2[l16] : 0.f;
    f32x4 acc0 = {0,0,0,0}, acc1 = {0,0,0,0};
    short8 a;
    a = *(const short8*)&s_hb[arow0*HB + q*8];      acc0 = __builtin_amdgcn_mfma_f32_16x16x32_bf16(a, bf0, acc0, 0, 0, 0);
    a = *(const short8*)&s_hb[arow0*HB + 32 + q*8]; acc0 = __builtin_amdgcn_mfma_f32_16x16x32_bf16(a, bf1, acc0, 0, 0, 0);
    a = *(const short8*)&s_hb[arow1*HB + q*8];      acc1 = __builtin_amdgcn_mfma_f32_16x16x32_bf16(a, bf0, acc1, 0, 0, 0);
    a = *(const short8*)&s_hb[arow1*HB + 32 + q*8]; acc1 = __builtin_amdgcn_mfma_f32_16x16x32_bf16(a, bf1, acc1, 0, 0, 0);
    if (l16 < 6) {
#pragma unroll
      for (int r = 0; r < 4; ++r) {
        const int row = q*4 + r;
        out[b*144 + row*6 + l16] = acc0[r] + bv;
      }
      if (q < 2) {
#pragma unroll
        for (int r = 0; r < 4; ++r) {
          const int row = 16 + q*4 + r;
          out[b*144 + row*6 + l16] = acc1[r] + bv;
        }
      }
    }
  }
}

extern "C" void kernel_launch(void* const* d_in, const int* in_sizes, int n_in,
                              void* d_out, int out_size, void* d_ws, size_t ws_size,
                              hipStream_t stream) {
  (void)n_in; (void)out_size; (void)d_ws; (void)ws_size;
  const float* x     = (const float*)d_in[0];
  const float* in_w  = (const float*)d_in[1];
  const float* in_b  = (const float*)d_in[2];
  const float* res_w = (const float*)d_in[3];
  const float* res_b = (const float*)d_in[4];
  const float* pos   = (const float*)d_in[5];
  const float* gat_w = (const float*)d_in[6];
  const float* att_s = (const float*)d_in[7];
  const float* att_d = (const float*)d_in[8];
  const float* gat_b = (const float*)d_in[9];
  const float* ln_g  = (const float*)d_in[10];
  const float* ln_b  = (const float*)d_in[11];
  const float* w1    = (const float*)d_in[12];
  const float* b1    = (const float*)d_in[13];
  const float* lng2  = (const float*)d_in[14];
  const float* lnb2  = (const float*)d_in[15];
  const float* w2    = (const float*)d_in[16];
  const float* b2    = (const float*)d_in[17];
  float* out = (float*)d_out;

  const int B = in_sizes[0] / (J*3);
  hipLaunchKernelGGL(prep_weights, dim3((64512 + 255)/256), dim3(256), 0, stream,
                     gat_w, att_s, att_d, w1, w2);
  hipLaunchKernelGGL(gat_fused, dim3(B/2), dim3(128), 0, stream,
                     x, in_w, in_b, res_w, res_b, pos, gat_b, ln_g, ln_b,
                     b1, lng2, lnb2, b2, out);
}

// Round 8
// 571.973 us; speedup vs baseline: 1.2661x; 1.2661x over previous
//
#include <hip/hip_runtime.h>

// GATRotationRegressor — round 8: TWO batch elements per wave (M=48 = 3 dense
// 16-row MFMA tiles), bf16 residual master in LDS (no vh register array).
// One 64-thread block = one wave = 2 batch elements.
// B=16384, J=24, IN=3, H=128, HEADS=4, C=32, OUT=6, L=3.

#define J 24
#define ROWS 48  // 2 batches * 24 joints
#define HB 136   // bf16 LDS row stride in shorts (272 B, 16B-aligned)
#define YS 68    // fp32 overlay row stride in words (= HB shorts)

typedef __attribute__((ext_vector_type(8))) short short8;
typedef __attribute__((ext_vector_type(4))) float f32x4;

// bf16 weights prepared once per launch:
// [0)      Wt[l][n][k]   3*128*128 = 49152
// [49152)  w1t[m][k]     64*128    = 8192
// [57344)  wa[l][j][k]   3*16*128  = 6144  (j<4: a_s head j; 4..7: a_d; 8..15: 0)
// [63488)  w2t[o][m]     16*64     = 1024  (o<6 real, else 0)
__device__ unsigned short g_wt[64512];

__constant__ int c_deg[J] = {4,3,3,3,3,3,3,3,3,5,2,2,3,3,3,2,3,3,3,3,3,3,2,2};
__constant__ int c_inc[J][5] = {
  {1,2,3,0,0},{0,4,1,0,0},{0,5,2,0,0},{0,6,3,0,0},{1,7,4,0,0},{2,8,5,0,0},
  {3,9,6,0,0},{4,10,7,0,0},{5,11,8,0,0},{6,12,13,14,9},{7,10,0,0,0},{8,11,0,0,0},
  {9,15,12,0,0},{9,16,13,0,0},{9,17,14,0,0},{12,15,0,0,0},{13,18,16,0,0},{14,19,17,0,0},
  {16,20,18,0,0},{17,21,19,0,0},{18,22,20,0,0},{19,23,21,0,0},{20,22,0,0,0},{21,23,0,0,0}
};

__device__ __forceinline__ unsigned short f2bf(float f) {
  unsigned u = __builtin_bit_cast(unsigned, f);
  u = (u + 0x7FFFu + ((u >> 16) & 1u)) >> 16;   // RNE
  return (unsigned short)u;
}
__device__ __forceinline__ float bf2f(unsigned short u) {
  return __builtin_bit_cast(float, (unsigned)u << 16);
}

__global__ __launch_bounds__(256) void prep_weights(
    const float* __restrict__ gat_w, const float* __restrict__ att_s,
    const float* __restrict__ att_d, const float* __restrict__ w1,
    const float* __restrict__ w2)
{
  const int idx = blockIdx.x * 256 + threadIdx.x;
  if (idx < 49152) {
    const int l = idx >> 14, rem = idx & 16383, n = rem >> 7, k = rem & 127;
    g_wt[idx] = f2bf(gat_w[l*16384 + k*128 + n]);
  } else if (idx < 57344) {
    const int i2 = idx - 49152, m = i2 >> 7, k = i2 & 127;
    g_wt[idx] = f2bf(w1[k*64 + m]);
  } else if (idx < 63488) {
    const int i2 = idx - 57344;
    const int l = i2 >> 11, r = i2 & 2047, j = r >> 7, k = r & 127;
    float v = 0.f;
    if (j < 8) {
      const int sd = j >> 2, hhh = j & 3;
      const float* av = (sd ? att_d : att_s) + (l*4 + hhh)*32;
      const float* wp = gat_w + l*16384 + k*128 + hhh*32;
#pragma unroll 8
      for (int c = 0; c < 32; ++c) v += wp[c] * av[c];
    }
    g_wt[idx] = f2bf(v);
  } else if (idx < 64512) {
    const int i2 = idx - 63488, o = i2 >> 6, m = i2 & 63;
    g_wt[idx] = f2bf(o < 6 ? w2[m*6 + o] : 0.f);
  }
}

__global__ __launch_bounds__(64) void gat_fused(
    const float* __restrict__ x,     const float* __restrict__ in_w,  const float* __restrict__ in_b,
    const float* __restrict__ res_w, const float* __restrict__ res_b, const float* __restrict__ pos,
    const float* __restrict__ gat_b, const float* __restrict__ ln_g,  const float* __restrict__ ln_b,
    const float* __restrict__ b1,    const float* __restrict__ lng2,  const float* __restrict__ lnb2,
    const float* __restrict__ b2,    float* __restrict__ out)
{
  __shared__ __align__(16) unsigned short s_hb [ROWS*HB];  // h bf16 master; later yln bf16
  __shared__ __align__(16) unsigned short s_xlb[ROWS*HB];  // xl bf16; later y1 fp32 overlay
  __shared__ float s_x[144];            // 2 batches * 24 joints * 3
  __shared__ float s_asd[ROWS*8];       // cols 0..3 a_s, 4..7 a_d
  __shared__ float s_alp[ROWS*20];      // alpha per (row, slot, head)

  const int tid = threadIdx.x;
  const long blk = blockIdx.x;          // covers batches 2*blk, 2*blk+1
  const int l16 = tid & 15, q = tid >> 4;
  const int g = tid >> 3, c8 = tid & 7, cb = c8*16, hh = c8 >> 1;

  // ---- P0: stage x for both batches (coalesced) ----
  {
    const float* xb = x + blk*144;
    s_x[tid]      = xb[tid];
    s_x[64 + tid] = xb[64 + tid];
    if (tid < 16) s_x[128 + tid] = xb[128 + tid];
  }
  __syncthreads();

  // ---- P1: input projection -> s_hb (bf16), 6 rows/thread ----
#pragma unroll
  for (int i = 0; i < 6; ++i) {
    const int r = g + 8*i;
    const int bp = (i < 3) ? 0 : 1;     // r<24 for i<3
    const int j = r - 24*bp;
    const float x0 = s_x[bp*72 + j*3], x1 = s_x[bp*72 + j*3 + 1], x2 = s_x[bp*72 + j*3 + 2];
    short8 p0, p1;
#pragma unroll
    for (int c4 = 0; c4 < 4; ++c4) {
      const float4 w0 = *(const float4*)&in_w[      cb + c4*4];
      const float4 w1v= *(const float4*)&in_w[128 + cb + c4*4];
      const float4 w2v= *(const float4*)&in_w[256 + cb + c4*4];
      const float4 bb = *(const float4*)&in_b[      cb + c4*4];
      const float4 pp = *(const float4*)&pos[j*128 + cb + c4*4];
      float v[4];
      v[0] = x0*w0.x + x1*w1v.x + x2*w2v.x + bb.x + pp.x;
      v[1] = x0*w0.y + x1*w1v.y + x2*w2v.y + bb.y + pp.y;
      v[2] = x0*w0.z + x1*w1v.z + x2*w2v.z + bb.z + pp.z;
      v[3] = x0*w0.w + x1*w1v.w + x2*w2v.w + bb.w + pp.w;
#pragma unroll
      for (int cc = 0; cc < 4; ++cc) {
        const int c = c4*4 + cc;
        if (c < 8) p0[c] = (short)f2bf(v[cc]); else p1[c-8] = (short)f2bf(v[cc]);
      }
    }
    *(short8*)&s_hb[r*HB + cb]     = p0;
    *(short8*)&s_hb[r*HB + cb + 8] = p1;
  }
  __syncthreads();

  // ---- GAT layers ----
  for (int l = 0; l < 3; ++l) {
    // === L1: xl = h@W (3 dense M-tiles) + fused logits ===
    {
      const unsigned short* Wl = &g_wt[l*16384];
      short8 af[3][4];
#pragma unroll
      for (int t = 0; t < 3; ++t)
#pragma unroll
        for (int ks = 0; ks < 4; ++ks)
          af[t][ks] = *(const short8*)&s_hb[(t*16 + l16)*HB + ks*32 + q*8];

#pragma unroll
      for (int nt = 0; nt < 8; ++nt) {
        f32x4 acc[3] = { {0,0,0,0}, {0,0,0,0}, {0,0,0,0} };
#pragma unroll
        for (int ks = 0; ks < 4; ++ks) {
          const short8 bfr = *(const short8*)&Wl[(nt*16 + l16)*128 + ks*32 + q*8];
#pragma unroll
          for (int t = 0; t < 3; ++t)
            acc[t] = __builtin_amdgcn_mfma_f32_16x16x32_bf16(af[t][ks], bfr, acc[t], 0, 0, 0);
        }
        const int col = nt*16 + l16;
#pragma unroll
        for (int t = 0; t < 3; ++t)
#pragma unroll
          for (int r4 = 0; r4 < 4; ++r4)
            s_xlb[(t*16 + q*4 + r4)*HB + col] = f2bf(acc[t][r4]);
      }
      // logits
      const unsigned short* Wa = &g_wt[57344 + l*2048];
      f32x4 la[3] = { {0,0,0,0}, {0,0,0,0}, {0,0,0,0} };
#pragma unroll
      for (int ks = 0; ks < 4; ++ks) {
        const short8 ba = *(const short8*)&Wa[l16*128 + ks*32 + q*8];
#pragma unroll
        for (int t = 0; t < 3; ++t)
          la[t] = __builtin_amdgcn_mfma_f32_16x16x32_bf16(af[t][ks], ba, la[t], 0, 0, 0);
      }
      if (l16 < 8) {
#pragma unroll
        for (int t = 0; t < 3; ++t)
#pragma unroll
          for (int r4 = 0; r4 < 4; ++r4)
            s_asd[(t*16 + q*4 + r4)*8 + l16] = la[t][r4];
      }
    }
    __syncthreads();

    // === L2: scatter-softmax (192 items = 48 rows * 4 heads; 3 full passes) ===
#pragma unroll
    for (int it = 0; it < 3; ++it) {
      const int item = tid + it*64;
      const int r = item >> 2, hh2 = item & 3;
      const int base = (r >= 24) ? 24 : 0, j = r - base;
      const int dg = c_deg[j];
      const float ad = s_asd[r*8 + 4 + hh2];
      float ev[5];
      float m = -1e30f;
#pragma unroll
      for (int e = 0; e < 5; ++e) if (e < dg) {
        float ee = s_asd[(base + c_inc[j][e])*8 + hh2] + ad;
        ee = (ee >= 0.f) ? ee : 0.2f*ee;
        ev[e] = ee;
        m = fmaxf(m, ee);
      }
      float den = 0.f;
#pragma unroll
      for (int e = 0; e < 5; ++e) if (e < dg) { ev[e] = __expf(ev[e]-m); den += ev[e]; }
      const float inv = 1.f/den;
#pragma unroll
      for (int e = 0; e < 5; ++e) if (e < dg) s_alp[(r*5+e)*4 + hh2] = ev[e]*inv;
    }
    __syncthreads();

    // === L3: aggregate + elu + LN (shfl stats) + apply (+res at l==2) ===
#pragma unroll
    for (int i = 0; i < 6; ++i) {
      const int r = g + 8*i;
      const int bp = (i < 3) ? 0 : 1;
      const int base = 24*bp, j = r - base;
      const int dg = c_deg[j];
      float ov[16];
#pragma unroll
      for (int c4 = 0; c4 < 4; ++c4) {
        const float4 gb4 = *(const float4*)&gat_b[l*128 + cb + c4*4];
        ov[c4*4+0]=gb4.x; ov[c4*4+1]=gb4.y; ov[c4*4+2]=gb4.z; ov[c4*4+3]=gb4.w;
      }
#pragma unroll
      for (int e = 0; e < 5; ++e) if (e < dg) {
        const float al = s_alp[(r*5+e)*4 + hh];
        const unsigned short* xp = &s_xlb[(base + c_inc[j][e])*HB + cb];
        const short8 xa = *(const short8*)xp;
        const short8 xb = *(const short8*)(xp + 8);
#pragma unroll
        for (int c = 0; c < 8; ++c) {
          ov[c]   += al * bf2f((unsigned short)xa[c]);
          ov[8+c] += al * bf2f((unsigned short)xb[c]);
        }
      }
      float s = 0.f, s2 = 0.f;
#pragma unroll
      for (int c = 0; c < 16; ++c) {
        float v = ov[c];
        v = (v > 0.f) ? v : (__expf(v) - 1.f);   // elu
        ov[c] = v;
        s += v; s2 += v*v;
      }
#pragma unroll
      for (int off = 1; off < 8; off <<= 1) {
        s  += __shfl_xor(s,  off, 64);
        s2 += __shfl_xor(s2, off, 64);
      }
      const float mean = s * (1.f/128.f);
      const float rstd = rsqrtf(s2 * (1.f/128.f) - mean*mean + 1e-5f);

      // previous h (bf16 master) for residual
      float hp[16];
      if (l > 0) {
        const unsigned short* hpp = &s_hb[r*HB + cb];
        const short8 ha = *(const short8*)hpp;
        const short8 hb2 = *(const short8*)(hpp + 8);
#pragma unroll
        for (int c = 0; c < 8; ++c) { hp[c] = bf2f((unsigned short)ha[c]); hp[8+c] = bf2f((unsigned short)hb2[c]); }
      }

      short8 p0, p1;
      if (l == 2) {
        const float x0 = s_x[bp*72 + j*3], x1 = s_x[bp*72 + j*3 + 1], x2 = s_x[bp*72 + j*3 + 2];
#pragma unroll
        for (int c4 = 0; c4 < 4; ++c4) {
          const float4 lg4 = *(const float4*)&ln_g[l*128 + cb + c4*4];
          const float4 lb4 = *(const float4*)&ln_b[l*128 + cb + c4*4];
          const float4 rw0 = *(const float4*)&res_w[      cb + c4*4];
          const float4 rw1 = *(const float4*)&res_w[128 + cb + c4*4];
          const float4 rw2 = *(const float4*)&res_w[256 + cb + c4*4];
          const float4 rb4 = *(const float4*)&res_b[      cb + c4*4];
          const float lgv[4] = {lg4.x, lg4.y, lg4.z, lg4.w};
          const float lbv[4] = {lb4.x, lb4.y, lb4.z, lb4.w};
          const float r0[4]  = {rw0.x, rw0.y, rw0.z, rw0.w};
          const float r1[4]  = {rw1.x, rw1.y, rw1.z, rw1.w};
          const float r2[4]  = {rw2.x, rw2.y, rw2.z, rw2.w};
          const float rb[4]  = {rb4.x, rb4.y, rb4.z, rb4.w};
#pragma unroll
          for (int cc = 0; cc < 4; ++cc) {
            const int c = c4*4 + cc;
            float v = (ov[c]-mean)*rstd*lgv[cc] + lbv[cc] + hp[c];
            v += x0*r0[cc] + x1*r1[cc] + x2*r2[cc] + rb[cc];
            if (c < 8) p0[c] = (short)f2bf(v); else p1[c-8] = (short)f2bf(v);
          }
        }
      } else {
#pragma unroll
        for (int c4 = 0; c4 < 4; ++c4) {
          const float4 lg4 = *(const float4*)&ln_g[l*128 + cb + c4*4];
          const float4 lb4 = *(const float4*)&ln_b[l*128 + cb + c4*4];
          const float lgv[4] = {lg4.x, lg4.y, lg4.z, lg4.w};
          const float lbv[4] = {lb4.x, lb4.y, lb4.z, lb4.w};
#pragma unroll
          for (int cc = 0; cc < 4; ++cc) {
            const int c = c4*4 + cc;
            float v = (ov[c]-mean)*rstd*lgv[cc] + lbv[cc];
            if (l > 0) v += hp[c];
            if (c < 8) p0[c] = (short)f2bf(v); else p1[c-8] = (short)f2bf(v);
          }
        }
      }
      *(short8*)&s_hb[r*HB + cb]     = p0;
      *(short8*)&s_hb[r*HB + cb + 8] = p1;
    }
    __syncthreads();
  }

  // ---- F1: y1 = relu(h @ w1t + b1), fp32 -> overlay on s_xlb (N=64, stride YS) ----
  {
    const unsigned short* W1 = &g_wt[49152];
    float* s_y = (float*)s_xlb;
    short8 af[3][4];
#pragma unroll
    for (int t = 0; t < 3; ++t)
#pragma unroll
      for (int ks = 0; ks < 4; ++ks)
        af[t][ks] = *(const short8*)&s_hb[(t*16 + l16)*HB + ks*32 + q*8];
#pragma unroll
    for (int nt = 0; nt < 4; ++nt) {
      const float bv = b1[nt*16 + l16];
      f32x4 acc[3] = { {bv,bv,bv,bv}, {bv,bv,bv,bv}, {bv,bv,bv,bv} };
#pragma unroll
      for (int ks = 0; ks < 4; ++ks) {
        const short8 bfr = *(const short8*)&W1[(nt*16 + l16)*128 + ks*32 + q*8];
#pragma unroll
        for (int t = 0; t < 3; ++t)
          acc[t] = __builtin_amdgcn_mfma_f32_16x16x32_bf16(af[t][ks], bfr, acc[t], 0, 0, 0);
      }
      const int col = nt*16 + l16;
#pragma unroll
      for (int t = 0; t < 3; ++t)
#pragma unroll
        for (int r4 = 0; r4 < 4; ++r4)
          s_y[(t*16 + q*4 + r4)*YS + col] = fmaxf(acc[t][r4], 0.f);
    }
  }
  __syncthreads();

  // ---- F2: LN(64) + yln -> s_hb (bf16); 96 items = 48 rows * 2 halves ----
#pragma unroll
  for (int it = 0; it < 2; ++it) {
    const int item = tid + it*64;
    if (item < 96) {
      const int row = item >> 1, half = item & 1;
      const float* yr = (const float*)s_xlb + row*YS + half*32;
      float yv[32];
      float s = 0.f, s2 = 0.f;
#pragma unroll
      for (int c4 = 0; c4 < 8; ++c4) {
        const float4 v4 = *(const float4*)&yr[c4*4];
        yv[c4*4+0]=v4.x; yv[c4*4+1]=v4.y; yv[c4*4+2]=v4.z; yv[c4*4+3]=v4.w;
        s += v4.x+v4.y+v4.z+v4.w;
        s2 += v4.x*v4.x + v4.y*v4.y + v4.z*v4.z + v4.w*v4.w;
      }
      s  += __shfl_xor(s,  1, 64);
      s2 += __shfl_xor(s2, 1, 64);
      const float mean = s * (1.f/64.f);
      const float rstd = rsqrtf(s2 * (1.f/64.f) - mean*mean + 1e-5f);
      short8 pk[4];
#pragma unroll
      for (int c = 0; c < 32; ++c) {
        const int m = half*32 + c;
        const float yl = (yv[c]-mean)*rstd*lng2[m] + lnb2[m];
        pk[c >> 3][c & 7] = (short)f2bf(yl);
      }
#pragma unroll
      for (int p = 0; p < 4; ++p)
        *(short8*)&s_hb[row*HB + half*32 + p*8] = pk[p];
    }
  }
  __syncthreads();

  // ---- F3: out = yln @ w2t + b2 (M=48, N=6(16), K=64) ----
  {
    const unsigned short* W2 = &g_wt[63488];
    const short8 bf0 = *(const short8*)&W2[l16*64 + q*8];
    const short8 bf1 = *(const short8*)&W2[l16*64 + 32 + q*8];
    const float bv = (l16 < 6) ? b2[l16] : 0.f;
#pragma unroll
    for (int t = 0; t < 3; ++t) {
      f32x4 acc = {0,0,0,0};
      const short8 a0 = *(const short8*)&s_hb[(t*16 + l16)*HB + q*8];
      acc = __builtin_amdgcn_mfma_f32_16x16x32_bf16(a0, bf0, acc, 0, 0, 0);
      const short8 a1 = *(const short8*)&s_hb[(t*16 + l16)*HB + 32 + q*8];
      acc = __builtin_amdgcn_mfma_f32_16x16x32_bf16(a1, bf1, acc, 0, 0, 0);
      if (l16 < 6) {
#pragma unroll
        for (int r4 = 0; r4 < 4; ++r4) {
          const int row = t*16 + q*4 + r4;
          const int bp = (row >= 24) ? 1 : 0;
          const int jj = row - 24*bp;
          out[(blk*2 + bp)*144 + jj*6 + l16] = acc[r4] + bv;
        }
      }
    }
  }
}

extern "C" void kernel_launch(void* const* d_in, const int* in_sizes, int n_in,
                              void* d_out, int out_size, void* d_ws, size_t ws_size,
                              hipStream_t stream) {
  (void)n_in; (void)out_size; (void)d_ws; (void)ws_size;
  const float* x     = (const float*)d_in[0];
  const float* in_w  = (const float*)d_in[1];
  const float* in_b  = (const float*)d_in[2];
  const float* res_w = (const float*)d_in[3];
  const float* res_b = (const float*)d_in[4];
  const float* pos   = (const float*)d_in[5];
  const float* gat_w = (const float*)d_in[6];
  const float* att_s = (const float*)d_in[7];
  const float* att_d = (const float*)d_in[8];
  const float* gat_b = (const float*)d_in[9];
  const float* ln_g  = (const float*)d_in[10];
  const float* ln_b  = (const float*)d_in[11];
  const float* w1    = (const float*)d_in[12];
  const float* b1    = (const float*)d_in[13];
  const float* lng2  = (const float*)d_in[14];
  const float* lnb2  = (const float*)d_in[15];
  const float* w2    = (const float*)d_in[16];
  const float* b2    = (const float*)d_in[17];
  float* out = (float*)d_out;

  const int B = in_sizes[0] / (J*3);
  hipLaunchKernelGGL(prep_weights, dim3((64512 + 255)/256), dim3(256), 0, stream,
                     gat_w, att_s, att_d, w1, w2);
  hipLaunchKernelGGL(gat_fused, dim3(B/2), dim3(64), 0, stream,
                     x, in_w, in_b, res_w, res_b, pos, gat_b, ln_g, ln_b,
                     b1, lng2, lnb2, b2, out);
}

// Round 9
// 474.116 us; speedup vs baseline: 1.5275x; 1.2064x over previous
//
#include <hip/hip_runtime.h>

// GATRotationRegressor — round 9: small-code hypothesis. Rolled layer/nt/row
// loops (#pragma unroll 1), packed edge tables, softmax fused into L3,
// swapped-operand MFMAs (A=weights, B=h) so C-layout outputs write
// contiguously (b64/b128 instead of scalar LDS writes).
// One 64-thread block = one wave = 2 batch elements (M=48 = 3 dense tiles).
// B=16384, J=24, IN=3, H=128, HEADS=4, C=32, OUT=6, L=3.

#define J 24
#define ROWS 48  // 2 batches * 24 joints
#define HB 136   // bf16 LDS row stride in shorts (272 B, 16B-aligned)
#define YS 68    // fp32 overlay row stride in words (= HB shorts)

typedef __attribute__((ext_vector_type(8))) short short8;
typedef __attribute__((ext_vector_type(4))) float f32x4;

// bf16 weights prepared once per launch:
// [0)      Wt[l][n][k]   3*128*128 = 49152
// [49152)  w1t[m][k]     64*128    = 8192
// [57344)  wa[l][j][k]   3*16*128  = 6144  (j<4: a_s head j; 4..7: a_d; 8..15: 0)
// [63488)  w2t[o][m]     16*64     = 1024  (o<6 real, else 0)
__device__ unsigned short g_wt[64512];

// packed incidence: deg | inc0<<3 | inc1<<8 | inc2<<13 | inc3<<18 | inc4<<23
#define PK5(d,a,b,c,e,f) ((unsigned)(d)|((unsigned)(a)<<3)|((unsigned)(b)<<8)|((unsigned)(c)<<13)|((unsigned)(e)<<18)|((unsigned)(f)<<23))
__constant__ unsigned c_pack[J] = {
  PK5(4,1,2,3,0,0),  PK5(3,0,4,1,0,0),  PK5(3,0,5,2,0,0),  PK5(3,0,6,3,0,0),
  PK5(3,1,7,4,0,0),  PK5(3,2,8,5,0,0),  PK5(3,3,9,6,0,0),  PK5(3,4,10,7,0,0),
  PK5(3,5,11,8,0,0), PK5(5,6,12,13,14,9),PK5(2,7,10,0,0,0), PK5(2,8,11,0,0,0),
  PK5(3,9,15,12,0,0),PK5(3,9,16,13,0,0),PK5(3,9,17,14,0,0),PK5(2,12,15,0,0,0),
  PK5(3,13,18,16,0,0),PK5(3,14,19,17,0,0),PK5(3,16,20,18,0,0),PK5(3,17,21,19,0,0),
  PK5(3,18,22,20,0,0),PK5(3,19,23,21,0,0),PK5(2,20,22,0,0,0),PK5(2,21,23,0,0,0)
};

__device__ __forceinline__ unsigned short f2bf(float f) {
  unsigned u = __builtin_bit_cast(unsigned, f);
  u = (u + 0x7FFFu + ((u >> 16) & 1u)) >> 16;   // RNE
  return (unsigned short)u;
}
__device__ __forceinline__ unsigned pack2bf(float a, float b) {
  unsigned ua = __builtin_bit_cast(unsigned, a);
  unsigned ub = __builtin_bit_cast(unsigned, b);
  ua = (ua + 0x7FFFu + ((ua >> 16) & 1u)) >> 16;       // lo = bf(a)
  ub = (ub + 0x7FFFu + ((ub >> 16) & 1u)) & 0xFFFF0000u; // hi = bf(b)
  return ua | ub;
}
__device__ __forceinline__ float bf2f(unsigned short u) {
  return __builtin_bit_cast(float, (unsigned)u << 16);
}

__global__ __launch_bounds__(256) void prep_weights(
    const float* __restrict__ gat_w, const float* __restrict__ att_s,
    const float* __restrict__ att_d, const float* __restrict__ w1,
    const float* __restrict__ w2)
{
  const int idx = blockIdx.x * 256 + threadIdx.x;
  if (idx < 49152) {
    const int l = idx >> 14, rem = idx & 16383, n = rem >> 7, k = rem & 127;
    g_wt[idx] = f2bf(gat_w[l*16384 + k*128 + n]);
  } else if (idx < 57344) {
    const int i2 = idx - 49152, m = i2 >> 7, k = i2 & 127;
    g_wt[idx] = f2bf(w1[k*64 + m]);
  } else if (idx < 63488) {
    const int i2 = idx - 57344;
    const int l = i2 >> 11, r = i2 & 2047, j = r >> 7, k = r & 127;
    float v = 0.f;
    if (j < 8) {
      const int sd = j >> 2, hhh = j & 3;
      const float* av = (sd ? att_d : att_s) + (l*4 + hhh)*32;
      const float* wp = gat_w + l*16384 + k*128 + hhh*32;
#pragma unroll 8
      for (int c = 0; c < 32; ++c) v += wp[c] * av[c];
    }
    g_wt[idx] = f2bf(v);
  } else if (idx < 64512) {
    const int i2 = idx - 63488, o = i2 >> 6, m = i2 & 63;
    g_wt[idx] = f2bf(o < 6 ? w2[m*6 + o] : 0.f);
  }
}

__global__ __launch_bounds__(64) void gat_fused(
    const float* __restrict__ x,     const float* __restrict__ in_w,  const float* __restrict__ in_b,
    const float* __restrict__ res_w, const float* __restrict__ res_b, const float* __restrict__ pos,
    const float* __restrict__ gat_b, const float* __restrict__ ln_g,  const float* __restrict__ ln_b,
    const float* __restrict__ b1,    const float* __restrict__ lng2,  const float* __restrict__ lnb2,
    const float* __restrict__ b2,    float* __restrict__ out)
{
  __shared__ __align__(16) unsigned short s_hb [ROWS*HB];  // h bf16 master; later yln bf16
  __shared__ __align__(16) unsigned short s_xlb[ROWS*HB];  // xl bf16; later y1 fp32 overlay
  __shared__ float s_x[144];        // 2 batches * 24 joints * 3
  __shared__ float s_asd[ROWS*8];   // cols 0..3 a_s, 4..7 a_d

  const int tid = threadIdx.x;
  const long blk = blockIdx.x;      // covers batches 2*blk, 2*blk+1
  const int l16 = tid & 15, q = tid >> 4;
  const int g = tid >> 3, c8 = tid & 7, cb = c8*16, hh = c8 >> 1;

  // ---- P0: stage x for both batches (coalesced) ----
  {
    const float* xb = x + blk*144;
    s_x[tid]      = xb[tid];
    s_x[64 + tid] = xb[64 + tid];
    if (tid < 16) s_x[128 + tid] = xb[128 + tid];
  }
  __syncthreads();

  // ---- P1: input projection -> s_hb (bf16), rolled over 6 rows/thread ----
#pragma unroll 1
  for (int i = 0; i < 6; ++i) {
    const int r = g + 8*i;
    const int bp = (r >= 24) ? 1 : 0;
    const int j = r - 24*bp;
    const float x0 = s_x[bp*72 + j*3], x1 = s_x[bp*72 + j*3 + 1], x2 = s_x[bp*72 + j*3 + 2];
    float v[16];
#pragma unroll
    for (int c4 = 0; c4 < 4; ++c4) {
      const float4 w0 = *(const float4*)&in_w[      cb + c4*4];
      const float4 w1v= *(const float4*)&in_w[128 + cb + c4*4];
      const float4 w2v= *(const float4*)&in_w[256 + cb + c4*4];
      const float4 bb = *(const float4*)&in_b[      cb + c4*4];
      const float4 pp = *(const float4*)&pos[j*128 + cb + c4*4];
      v[c4*4+0] = x0*w0.x + x1*w1v.x + x2*w2v.x + bb.x + pp.x;
      v[c4*4+1] = x0*w0.y + x1*w1v.y + x2*w2v.y + bb.y + pp.y;
      v[c4*4+2] = x0*w0.z + x1*w1v.z + x2*w2v.z + bb.z + pp.z;
      v[c4*4+3] = x0*w0.w + x1*w1v.w + x2*w2v.w + bb.w + pp.w;
    }
    uint4 pk0, pk1;
    pk0.x = pack2bf(v[0],v[1]);   pk0.y = pack2bf(v[2],v[3]);
    pk0.z = pack2bf(v[4],v[5]);   pk0.w = pack2bf(v[6],v[7]);
    pk1.x = pack2bf(v[8],v[9]);   pk1.y = pack2bf(v[10],v[11]);
    pk1.z = pack2bf(v[12],v[13]); pk1.w = pack2bf(v[14],v[15]);
    *(uint4*)&s_hb[r*HB + cb]     = pk0;
    *(uint4*)&s_hb[r*HB + cb + 8] = pk1;
  }
  __syncthreads();

  // ---- GAT layers (rolled) ----
#pragma unroll 1
  for (int l = 0; l < 3; ++l) {
    // h fragments (B-operand layout == A-layout of h rows)
    short8 af[3][4];
#pragma unroll
    for (int t = 0; t < 3; ++t)
#pragma unroll
      for (int ks = 0; ks < 4; ++ks)
        af[t][ks] = *(const short8*)&s_hb[(t*16 + l16)*HB + ks*32 + q*8];

    // === L1: xl^T-tiles = mfma(A=Wt, B=h) -> contiguous-column writes ===
    {
      const unsigned short* Wl = &g_wt[l*16384];
#pragma unroll 1
      for (int nt = 0; nt < 8; ++nt) {
        f32x4 acc[3] = { {0,0,0,0}, {0,0,0,0}, {0,0,0,0} };
#pragma unroll
        for (int ks = 0; ks < 4; ++ks) {
          const short8 bfr = *(const short8*)&Wl[(nt*16 + l16)*128 + ks*32 + q*8];
#pragma unroll
          for (int t = 0; t < 3; ++t)
            acc[t] = __builtin_amdgcn_mfma_f32_16x16x32_bf16(bfr, af[t][ks], acc[t], 0, 0, 0);
        }
#pragma unroll
        for (int t = 0; t < 3; ++t) {
          uint2 w;
          w.x = pack2bf(acc[t][0], acc[t][1]);
          w.y = pack2bf(acc[t][2], acc[t][3]);
          *(uint2*)&s_xlb[(t*16 + l16)*HB + nt*16 + q*4] = w;
        }
      }
      // logits: D[m=wa-col][n=h-row]; q<2 holds cols 0..7
      const unsigned short* Wa = &g_wt[57344 + l*2048];
      f32x4 la[3] = { {0,0,0,0}, {0,0,0,0}, {0,0,0,0} };
#pragma unroll
      for (int ks = 0; ks < 4; ++ks) {
        const short8 ba = *(const short8*)&Wa[l16*128 + ks*32 + q*8];
#pragma unroll
        for (int t = 0; t < 3; ++t)
          la[t] = __builtin_amdgcn_mfma_f32_16x16x32_bf16(ba, af[t][ks], la[t], 0, 0, 0);
      }
      if (q < 2) {
#pragma unroll
        for (int t = 0; t < 3; ++t) {
          float4 w; w.x = la[t][0]; w.y = la[t][1]; w.z = la[t][2]; w.w = la[t][3];
          *(float4*)&s_asd[(t*16 + l16)*8 + q*4] = w;
        }
      }
    }
    __syncthreads();

    // === L3: inline softmax + aggregate + elu + LN + apply (+res at l==2) ===
#pragma unroll 1
    for (int i = 0; i < 6; ++i) {
      const int r = g + 8*i;
      const int bp = (r >= 24) ? 1 : 0;
      const int base = 24*bp, j = r - base;
      const unsigned pkw = c_pack[j];
      const int dg = pkw & 7;
      const unsigned pp = pkw >> 3;

      // softmax over incoming edges for (row r, head hh)
      const float ad = s_asd[r*8 + 4 + hh];
      float al[5];
      float mx = -1e30f;
#pragma unroll
      for (int e = 0; e < 5; ++e) if (e < dg) {
        const int src = (pp >> (5*e)) & 31;
        float ee = s_asd[(base + src)*8 + hh] + ad;
        ee = (ee >= 0.f) ? ee : 0.2f*ee;
        al[e] = ee;
        mx = fmaxf(mx, ee);
      }
      float den = 0.f;
#pragma unroll
      for (int e = 0; e < 5; ++e) if (e < dg) { al[e] = __expf(al[e]-mx); den += al[e]; }
      const float inv = 1.f/den;

      float ov[16];
#pragma unroll
      for (int c4 = 0; c4 < 4; ++c4) {
        const float4 gb4 = *(const float4*)&gat_b[l*128 + cb + c4*4];
        ov[c4*4+0]=gb4.x; ov[c4*4+1]=gb4.y; ov[c4*4+2]=gb4.z; ov[c4*4+3]=gb4.w;
      }
#pragma unroll
      for (int e = 0; e < 5; ++e) if (e < dg) {
        const float a = al[e]*inv;
        const int src = (pp >> (5*e)) & 31;
        const unsigned short* xp = &s_xlb[(base + src)*HB + cb];
        const short8 xa = *(const short8*)xp;
        const short8 xb = *(const short8*)(xp + 8);
#pragma unroll
        for (int c = 0; c < 8; ++c) {
          ov[c]   += a * bf2f((unsigned short)xa[c]);
          ov[8+c] += a * bf2f((unsigned short)xb[c]);
        }
      }
      float s = 0.f, s2 = 0.f;
#pragma unroll
      for (int c = 0; c < 16; ++c) {
        float v = ov[c];
        v = (v > 0.f) ? v : (__expf(v) - 1.f);   // elu
        ov[c] = v;
        s += v; s2 += v*v;
      }
#pragma unroll
      for (int off = 1; off < 8; off <<= 1) {
        s  += __shfl_xor(s,  off, 64);
        s2 += __shfl_xor(s2, off, 64);
      }
      const float mean = s * (1.f/128.f);
      const float rstd = rsqrtf(s2 * (1.f/128.f) - mean*mean + 1e-5f);

      // previous h for residual (bf16 master)
      float hp[16];
      {
        const unsigned short* hpp = &s_hb[r*HB + cb];
        const short8 ha = *(const short8*)hpp;
        const short8 hb2 = *(const short8*)(hpp + 8);
#pragma unroll
        for (int c = 0; c < 8; ++c) { hp[c] = bf2f((unsigned short)ha[c]); hp[8+c] = bf2f((unsigned short)hb2[c]); }
      }

#pragma unroll
      for (int c4 = 0; c4 < 4; ++c4) {
        const float4 lg4 = *(const float4*)&ln_g[l*128 + cb + c4*4];
        const float4 lb4 = *(const float4*)&ln_b[l*128 + cb + c4*4];
        const float lgv[4] = {lg4.x, lg4.y, lg4.z, lg4.w};
        const float lbv[4] = {lb4.x, lb4.y, lb4.z, lb4.w};
#pragma unroll
        for (int cc = 0; cc < 4; ++cc) {
          const int c = c4*4 + cc;
          float v = (ov[c]-mean)*rstd*lgv[cc] + lbv[cc];
          if (l > 0) v += hp[c];
          ov[c] = v;
        }
      }
      if (l == 2) {   // fold h += res into last layer's apply
        const float x0 = s_x[bp*72 + j*3], x1 = s_x[bp*72 + j*3 + 1], x2 = s_x[bp*72 + j*3 + 2];
#pragma unroll
        for (int c4 = 0; c4 < 4; ++c4) {
          const float4 rw0 = *(const float4*)&res_w[      cb + c4*4];
          const float4 rw1 = *(const float4*)&res_w[128 + cb + c4*4];
          const float4 rw2 = *(const float4*)&res_w[256 + cb + c4*4];
          const float4 rb4 = *(const float4*)&res_b[      cb + c4*4];
          ov[c4*4+0] += x0*rw0.x + x1*rw1.x + x2*rw2.x + rb4.x;
          ov[c4*4+1] += x0*rw0.y + x1*rw1.y + x2*rw2.y + rb4.y;
          ov[c4*4+2] += x0*rw0.z + x1*rw1.z + x2*rw2.z + rb4.z;
          ov[c4*4+3] += x0*rw0.w + x1*rw1.w + x2*rw2.w + rb4.w;
        }
      }
      uint4 pk0, pk1;
      pk0.x = pack2bf(ov[0],ov[1]);   pk0.y = pack2bf(ov[2],ov[3]);
      pk0.z = pack2bf(ov[4],ov[5]);   pk0.w = pack2bf(ov[6],ov[7]);
      pk1.x = pack2bf(ov[8],ov[9]);   pk1.y = pack2bf(ov[10],ov[11]);
      pk1.z = pack2bf(ov[12],ov[13]); pk1.w = pack2bf(ov[14],ov[15]);
      *(uint4*)&s_hb[r*HB + cb]     = pk0;
      *(uint4*)&s_hb[r*HB + cb + 8] = pk1;
    }
    __syncthreads();
  }

  // ---- F1: y1 = relu(h @ w1t + b1) swapped -> float4 writes, stride YS ----
  {
    const unsigned short* W1 = &g_wt[49152];
    float* s_y = (float*)s_xlb;
    short8 af[3][4];
#pragma unroll
    for (int t = 0; t < 3; ++t)
#pragma unroll
      for (int ks = 0; ks < 4; ++ks)
        af[t][ks] = *(const short8*)&s_hb[(t*16 + l16)*HB + ks*32 + q*8];
#pragma unroll 1
    for (int nt = 0; nt < 4; ++nt) {
      const float4 b1v = *(const float4*)&b1[nt*16 + q*4];
      f32x4 acc[3];
#pragma unroll
      for (int t = 0; t < 3; ++t) { acc[t][0]=b1v.x; acc[t][1]=b1v.y; acc[t][2]=b1v.z; acc[t][3]=b1v.w; }
#pragma unroll
      for (int ks = 0; ks < 4; ++ks) {
        const short8 bfr = *(const short8*)&W1[(nt*16 + l16)*128 + ks*32 + q*8];
#pragma unroll
        for (int t = 0; t < 3; ++t)
          acc[t] = __builtin_amdgcn_mfma_f32_16x16x32_bf16(bfr, af[t][ks], acc[t], 0, 0, 0);
      }
#pragma unroll
      for (int t = 0; t < 3; ++t) {
        float4 w;
        w.x = fmaxf(acc[t][0], 0.f); w.y = fmaxf(acc[t][1], 0.f);
        w.z = fmaxf(acc[t][2], 0.f); w.w = fmaxf(acc[t][3], 0.f);
        *(float4*)&s_y[(t*16 + l16)*YS + nt*16 + q*4] = w;
      }
    }
  }
  __syncthreads();

  // ---- F2: LN(64) + yln -> s_hb (bf16); 96 items = 48 rows * 2 halves ----
#pragma unroll 1
  for (int it = 0; it < 2; ++it) {
    const int item = tid + it*64;
    if (item < 96) {
      const int row = item >> 1, half = item & 1;
      const float* yr = (const float*)s_xlb + row*YS + half*32;
      float yv[32];
      float s = 0.f, s2 = 0.f;
#pragma unroll
      for (int c4 = 0; c4 < 8; ++c4) {
        const float4 v4 = *(const float4*)&yr[c4*4];
        yv[c4*4+0]=v4.x; yv[c4*4+1]=v4.y; yv[c4*4+2]=v4.z; yv[c4*4+3]=v4.w;
        s += v4.x+v4.y+v4.z+v4.w;
        s2 += v4.x*v4.x + v4.y*v4.y + v4.z*v4.z + v4.w*v4.w;
      }
      s  += __shfl_xor(s,  1, 64);
      s2 += __shfl_xor(s2, 1, 64);
      const float mean = s * (1.f/64.f);
      const float rstd = rsqrtf(s2 * (1.f/64.f) - mean*mean + 1e-5f);
      float yl[32];
#pragma unroll
      for (int c = 0; c < 32; ++c) {
        const int m = half*32 + c;
        yl[c] = (yv[c]-mean)*rstd*lng2[m] + lnb2[m];
      }
      uint4 pkA, pkB;
      pkA.x = pack2bf(yl[0],yl[1]);   pkA.y = pack2bf(yl[2],yl[3]);
      pkA.z = pack2bf(yl[4],yl[5]);   pkA.w = pack2bf(yl[6],yl[7]);
      pkB.x = pack2bf(yl[8],yl[9]);   pkB.y = pack2bf(yl[10],yl[11]);
      pkB.z = pack2bf(yl[12],yl[13]); pkB.w = pack2bf(yl[14],yl[15]);
      *(uint4*)&s_hb[row*HB + half*32]     = pkA;
      *(uint4*)&s_hb[row*HB + half*32 + 8] = pkB;
      pkA.x = pack2bf(yl[16],yl[17]); pkA.y = pack2bf(yl[18],yl[19]);
      pkA.z = pack2bf(yl[20],yl[21]); pkA.w = pack2bf(yl[22],yl[23]);
      pkB.x = pack2bf(yl[24],yl[25]); pkB.y = pack2bf(yl[26],yl[27]);
      pkB.z = pack2bf(yl[28],yl[29]); pkB.w = pack2bf(yl[30],yl[31]);
      *(uint4*)&s_hb[row*HB + half*32 + 16] = pkA;
      *(uint4*)&s_hb[row*HB + half*32 + 24] = pkB;
    }
  }
  __syncthreads();

  // ---- F3: out = yln @ w2t + b2, swapped: lane l16 = row, q*4+rr = o ----
  {
    const unsigned short* W2 = &g_wt[63488];
    const short8 bf0 = *(const short8*)&W2[l16*64 + q*8];
    const short8 bf1 = *(const short8*)&W2[l16*64 + 32 + q*8];
#pragma unroll 1
    for (int t = 0; t < 3; ++t) {
      f32x4 acc = {0,0,0,0};
      const short8 a0 = *(const short8*)&s_hb[(t*16 + l16)*HB + q*8];
      acc = __builtin_amdgcn_mfma_f32_16x16x32_bf16(bf0, a0, acc, 0, 0, 0);
      const short8 a1 = *(const short8*)&s_hb[(t*16 + l16)*HB + 32 + q*8];
      acc = __builtin_amdgcn_mfma_f32_16x16x32_bf16(bf1, a1, acc, 0, 0, 0);
      const int row = t*16 + l16;
      const int bp = (row >= 24) ? 1 : 0;
      const int jj = row - 24*bp;
      float* op = out + (blk*2 + bp)*144 + jj*6;
      if (q == 0) {
        float4 w;
        w.x = acc[0] + b2[0]; w.y = acc[1] + b2[1];
        w.z = acc[2] + b2[2]; w.w = acc[3] + b2[3];
        *(float4*)op = w;
      } else if (q == 1) {
        float2 w;
        w.x = acc[0] + b2[4]; w.y = acc[1] + b2[5];
        *(float2*)(op + 4) = w;
      }
    }
  }
}

extern "C" void kernel_launch(void* const* d_in, const int* in_sizes, int n_in,
                              void* d_out, int out_size, void* d_ws, size_t ws_size,
                              hipStream_t stream) {
  (void)n_in; (void)out_size; (void)d_ws; (void)ws_size;
  const float* x     = (const float*)d_in[0];
  const float* in_w  = (const float*)d_in[1];
  const float* in_b  = (const float*)d_in[2];
  const float* res_w = (const float*)d_in[3];
  const float* res_b = (const float*)d_in[4];
  const float* pos   = (const float*)d_in[5];
  const float* gat_w = (const float*)d_in[6];
  const float* att_s = (const float*)d_in[7];
  const float* att_d = (const float*)d_in[8];
  const float* gat_b = (const float*)d_in[9];
  const float* ln_g  = (const float*)d_in[10];
  const float* ln_b  = (const float*)d_in[11];
  const float* w1    = (const float*)d_in[12];
  const float* b1    = (const float*)d_in[13];
  const float* lng2  = (const float*)d_in[14];
  const float* lnb2  = (const float*)d_in[15];
  const float* w2    = (const float*)d_in[16];
  const float* b2    = (const float*)d_in[17];
  float* out = (float*)d_out;

  const int B = in_sizes[0] / (J*3);
  hipLaunchKernelGGL(prep_weights, dim3((64512 + 255)/256), dim3(256), 0, stream,
                     gat_w, att_s, att_d, w1, w2);
  hipLaunchKernelGGL(gat_fused, dim3(B/2), dim3(64), 0, stream,
                     x, in_w, in_b, res_w, res_b, pos, gat_b, ln_g, ln_b,
                     b1, lng2, lnb2, b2, out);
}